// Round 5
// baseline (57.675 us; speedup 1.0000x reference)
//
#include <hip/hip_runtime.h>
#include <hip/hip_bf16.h>
#include <stdint.h>
#include <math.h>

#define B_N 128
#define D_N 512
#define H_N 1024
#define C_N 1000
#define CP  1024   // padded row stride for logits/g
#define NPART 16   // K-split count for fc1 (d) and fc2 (j)
#define BH (B_N * H_N)

// ---------------------------------------------------------------------------
// threefry2x32 (JAX-compatible, 20 rounds) -- verified bit-exact (R1 absmax 0)
// ---------------------------------------------------------------------------
__device__ __forceinline__ uint32_t rotl32(uint32_t v, int r) {
  return (v << r) | (v >> (32 - r));
}

__device__ __forceinline__ void threefry2x32(uint32_t k0, uint32_t k1,
                                             uint32_t x0, uint32_t x1,
                                             uint32_t &o0, uint32_t &o1) {
  uint32_t ks2 = k0 ^ k1 ^ 0x1BD11BDAu;
#define TF_R(r) { x0 += x1; x1 = rotl32(x1, r); x1 ^= x0; }
  x0 += k0; x1 += k1;
  TF_R(13) TF_R(15) TF_R(26) TF_R(6)
  x0 += k1; x1 += ks2 + 1u;
  TF_R(17) TF_R(29) TF_R(16) TF_R(24)
  x0 += ks2; x1 += k0 + 2u;
  TF_R(13) TF_R(15) TF_R(26) TF_R(6)
  x0 += k0; x1 += k1 + 3u;
  TF_R(17) TF_R(29) TF_R(16) TF_R(24)
  x0 += k1; x1 += ks2 + 4u;
  TF_R(13) TF_R(15) TF_R(26) TF_R(6)
  x0 += ks2; x1 += k0 + 5u;
#undef TF_R
  o0 = x0; o1 = x1;
}

__device__ __forceinline__ float gumbel_from_key(uint32_t k0, uint32_t k1, uint32_t i) {
  uint32_t o0, o1;
  threefry2x32(k0, k1, 0u, i, o0, o1);
  uint32_t bits = o0 ^ o1;
  uint32_t fb = (bits >> 9) | 0x3f800000u;
  float f = __uint_as_float(fb) - 1.0f;            // [0, 1)
  const float tiny = 1.1754943508222875e-38f;
  float u = fmaxf(tiny, f * (1.0f - tiny) + tiny); // JAX uniform(minval=tiny)
  return -logf(-logf(u));
}

// ---------------------------------------------------------------------------
// block reductions (512 threads = 8 waves)
// ---------------------------------------------------------------------------
__device__ __forceinline__ float block_sum512(float v, float* red) {
  #pragma unroll
  for (int o = 32; o; o >>= 1) v += __shfl_xor(v, o);
  __syncthreads();
  if ((threadIdx.x & 63) == 0) red[threadIdx.x >> 6] = v;
  __syncthreads();
  return red[0] + red[1] + red[2] + red[3] + red[4] + red[5] + red[6] + red[7];
}

__device__ __forceinline__ float block_max512(float v, float* red) {
  #pragma unroll
  for (int o = 32; o; o >>= 1) v = fmaxf(v, __shfl_xor(v, o));
  __syncthreads();
  if ((threadIdx.x & 63) == 0) red[threadIdx.x >> 6] = v;
  __syncthreads();
  float m = red[0];
  #pragma unroll
  for (int w = 1; w < 8; w++) m = fmaxf(m, red[w]);
  return m;
}

// fma4: a += b * s (componentwise). Function, not macro -- a macro parameter
// named `w` would be substituted into the `.w` member access (R4 compile bug).
__device__ __forceinline__ void fma4(float4 &a, const float4 &b, float s) {
  a.x += b.x * s; a.y += b.y * s; a.z += b.z * s; a.w += b.w * s;
}

// ---------------------------------------------------------------------------
// K1: hpart[dz][s][c] partial of X @ W1 over d in [dz*32, dz*32+32).
// grid (4 ctile, 8 sgroup, 16 dsplit) = 512 blocks, 256 thr.
// Thread computes 4c x 4s via outer product; x broadcast from LDS transpose.
// Bias b1 applied by consumers.
// ---------------------------------------------------------------------------
__global__ __launch_bounds__(256) void k_fc1(const float* __restrict__ X,
                                             const float* __restrict__ W1,
                                             float* __restrict__ hpart) {
  __shared__ float xT[32 * 20];   // [d][s], stride 20 (16B-aligned float4 at s4)
  int cbase = blockIdx.x * 256;
  int sbase = blockIdx.y * 16;
  int dz = blockIdx.z;            // 0..15
  int t = threadIdx.x;
  {
    int s = t >> 4;               // 0..15
    int d2 = (t & 15) * 2;        // 0..30
    float2 xv = *reinterpret_cast<const float2*>(
        &X[(sbase + s) * D_N + dz * 32 + d2]);
    xT[(d2 + 0) * 20 + s] = xv.x;
    xT[(d2 + 1) * 20 + s] = xv.y;
  }
  __syncthreads();
  int c4 = cbase + (t & 63) * 4;
  int s4 = (t >> 6) * 4;
  float4 acc0 = {0,0,0,0}, acc1 = {0,0,0,0}, acc2 = {0,0,0,0}, acc3 = {0,0,0,0};
  const float* W1p = W1 + (size_t)(dz * 32) * H_N + c4;
  float4 wb[4], wn[4];
  #pragma unroll
  for (int i = 0; i < 4; i++)
    wb[i] = *reinterpret_cast<const float4*>(W1p + i * H_N);
  for (int j0 = 0; j0 < 32; j0 += 4) {
    #pragma unroll
    for (int i = 0; i < 4; i++) {
      int jn = j0 + 4 + i; jn = (jn < 32) ? jn : 31;
      wn[i] = *reinterpret_cast<const float4*>(W1p + jn * H_N);
    }
    #pragma unroll
    for (int i = 0; i < 4; i++) {
      float4 xv = *reinterpret_cast<const float4*>(&xT[(j0 + i) * 20 + s4]);
      fma4(acc0, wb[i], xv.x);
      fma4(acc1, wb[i], xv.y);
      fma4(acc2, wb[i], xv.z);
      fma4(acc3, wb[i], xv.w);
    }
    #pragma unroll
    for (int i = 0; i < 4; i++) wb[i] = wn[i];
  }
  float* hp = hpart + (size_t)dz * BH;
  *reinterpret_cast<float4*>(&hp[(sbase + s4 + 0) * H_N + c4]) = acc0;
  *reinterpret_cast<float4*>(&hp[(sbase + s4 + 1) * H_N + c4]) = acc1;
  *reinterpret_cast<float4*>(&hp[(sbase + s4 + 2) * H_N + c4]) = acc2;
  *reinterpret_cast<float4*>(&hp[(sbase + s4 + 3) * H_N + c4]) = acc3;
}

// ---------------------------------------------------------------------------
// K2: lpart[kb][s][c] partial of relu(h) @ W2 over j in [kb*64, kb*64+64).
// grid (4 ctile, 8 sgroup, 16 jsplit) = 512 blocks, 256 thr.
// h reconstructed from hpart (fixed order: b1 then p=0..15) with relu, staged
// transposed in LDS. b2 applied in k_sample.
// ---------------------------------------------------------------------------
__global__ __launch_bounds__(256) void k_fc2(const float* __restrict__ hpart,
                                             const float* __restrict__ b1,
                                             const float* __restrict__ W2,
                                             float* __restrict__ lpart) {
  __shared__ float hT[64 * 20];   // [j][s], stride 20
  int cbase = blockIdx.x * 256;
  int sbase = blockIdx.y * 16;
  int kb = blockIdx.z;            // 0..15
  int jbase = kb * 64;
  int t = threadIdx.x;
  #pragma unroll
  for (int k = 0; k < 4; k++) {
    int idx = t + k * 256;        // 0..1023
    int s = idx >> 6, j = idx & 63;
    float v = b1[jbase + j];
    #pragma unroll
    for (int p = 0; p < NPART; p++)
      v += hpart[(size_t)p * BH + (sbase + s) * H_N + jbase + j];
    hT[j * 20 + s] = fmaxf(v, 0.0f);
  }
  __syncthreads();
  int c4 = cbase + (t & 63) * 4;
  int s4 = (t >> 6) * 4;
  if (c4 < C_N) {
    float4 acc0 = {0,0,0,0}, acc1 = {0,0,0,0}, acc2 = {0,0,0,0}, acc3 = {0,0,0,0};
    const float* W2p = W2 + (size_t)jbase * C_N + c4;
    float4 wb[4], wn[4];
    #pragma unroll
    for (int i = 0; i < 4; i++)
      wb[i] = *reinterpret_cast<const float4*>(W2p + (size_t)i * C_N);
    for (int j0 = 0; j0 < 64; j0 += 4) {
      #pragma unroll
      for (int i = 0; i < 4; i++) {
        int jn = j0 + 4 + i; jn = (jn < 64) ? jn : 63;
        wn[i] = *reinterpret_cast<const float4*>(W2p + (size_t)jn * C_N);
      }
      #pragma unroll
      for (int i = 0; i < 4; i++) {
        float4 xv = *reinterpret_cast<const float4*>(&hT[(j0 + i) * 20 + s4]);
        fma4(acc0, wb[i], xv.x);
        fma4(acc1, wb[i], xv.y);
        fma4(acc2, wb[i], xv.z);
        fma4(acc3, wb[i], xv.w);
      }
      #pragma unroll
      for (int i = 0; i < 4; i++) wb[i] = wn[i];
    }
    float* lp = lpart + (size_t)kb * (B_N * CP);
    *reinterpret_cast<float4*>(&lp[(sbase + s4 + 0) * CP + c4]) = acc0;
    *reinterpret_cast<float4*>(&lp[(sbase + s4 + 1) * CP + c4]) = acc1;
    *reinterpret_cast<float4*>(&lp[(sbase + s4 + 2) * CP + c4]) = acc2;
    *reinterpret_cast<float4*>(&lp[(sbase + s4 + 3) * CP + c4]) = acc3;
  }
}

// ---------------------------------------------------------------------------
// K3: sum NPART logit partials + b2; categorical sample; softmax grad g;
// reconstruct hfinal (pre-relu) for bwd1 mask; W2/b2 trace partials.
// One block (512 thr) per sample.
// ---------------------------------------------------------------------------
__global__ __launch_bounds__(512) void k_sample(const float* __restrict__ X,
                                                const float* __restrict__ hpart,
                                                const float* __restrict__ b1,
                                                const float* __restrict__ lpart,
                                                const float* __restrict__ b2,
                                                float* __restrict__ g,
                                                float* __restrict__ hfinal,
                                                float* __restrict__ xsq_out,
                                                float* __restrict__ samp_part) {
  __shared__ float lg[C_N];
  __shared__ float red[8];
  __shared__ float redv[8];
  __shared__ int   redi[8];
  __shared__ uint32_t keys[2];
  int b = blockIdx.x;
  int t = threadIdx.x;

  {
    float sA = b2[t];
    float sB = (t + 512 < C_N) ? b2[t + 512] : 0.f;
    #pragma unroll
    for (int p = 0; p < NPART; p++) {
      const float* lp = lpart + (size_t)p * (B_N * CP) + b * CP;
      sA += lp[t];
      if (t + 512 < C_N) sB += lp[t + 512];
    }
    lg[t] = sA;
    if (t + 512 < C_N) lg[t + 512] = sB;
  }
  if (t == 0) {
    uint32_t o0, o1;
    threefry2x32(0u, 42u, 0u, (uint32_t)b, o0, o1);
    keys[0] = o0; keys[1] = o1;
  }
  __syncthreads();
  uint32_t k0 = keys[0], k1 = keys[1];

  // gumbel-argmax over 1000 classes
  float bz = -INFINITY; int bi = 0x7fffffff;
  {
    float z0 = lg[t] + gumbel_from_key(k0, k1, (uint32_t)t);
    bz = z0; bi = t;
    if (t + 512 < C_N) {
      float z1 = lg[t + 512] + gumbel_from_key(k0, k1, (uint32_t)(t + 512));
      if (z1 > bz || (z1 == bz && (t + 512) < bi)) { bz = z1; bi = t + 512; }
    }
  }
  #pragma unroll
  for (int o = 32; o; o >>= 1) {
    float ov = __shfl_xor(bz, o);
    int   oi = __shfl_xor(bi, o);
    if (ov > bz || (ov == bz && oi < bi)) { bz = ov; bi = oi; }
  }
  if ((t & 63) == 0) { redv[t >> 6] = bz; redi[t >> 6] = bi; }
  __syncthreads();
  if (t == 0) {
    #pragma unroll
    for (int w = 1; w < 8; w++) {
      if (redv[w] > redv[0] || (redv[w] == redv[0] && redi[w] < redi[0])) {
        redv[0] = redv[w]; redi[0] = redi[w];
      }
    }
  }
  __syncthreads();
  int y = redi[0];

  // softmax
  float lm = lg[t];
  if (t + 512 < C_N) lm = fmaxf(lm, lg[t + 512]);
  float m = block_max512(lm, red);
  float ea = expf(lg[t] - m);
  float eb = (t + 512 < C_N) ? expf(lg[t + 512] - m) : 0.0f;
  float sum1 = block_sum512(ea + eb, red);
  float inv = 1.0f / sum1;

  float ga  = ea * inv - ((t == y) ? 1.0f : 0.0f);
  float gb2 = eb * inv - (((t + 512) == y) ? 1.0f : 0.0f);
  g[b * CP + t] = ga;
  g[b * CP + t + 512] = (t + 512 < C_N) ? gb2 : 0.0f;  // zero-pad cols 1000..1023
  float gn = ga * ga + ((t + 512 < C_N) ? gb2 * gb2 : 0.0f);
  float tnorm = block_sum512(gn, red);   // ||g||^2

  // reconstruct h (pre-relu), write for bwd1 mask, accumulate ||relu(h)||^2
  float h0 = b1[t];
  float h1 = b1[t + 512];
  #pragma unroll
  for (int p = 0; p < NPART; p++) {
    const float* hp = hpart + (size_t)p * BH + b * H_N;
    h0 += hp[t];
    h1 += hp[t + 512];
  }
  hfinal[b * H_N + t] = h0;
  hfinal[b * H_N + t + 512] = h1;
  float r0 = fmaxf(h0, 0.f), r1 = fmaxf(h1, 0.f);
  float hsq = block_sum512(r0 * r0 + r1 * r1, red);

  // ||x||^2
  float xv = (t < D_N) ? X[b * D_N + t] : 0.0f;
  float xsq = block_sum512(xv * xv, red);

  if (t == 0) {
    xsq_out[b] = xsq;
    samp_part[b * 2 + 0] = hsq * tnorm;  // W2 trace numerator
    samp_part[b * 2 + 1] = tnorm;        // b2 trace numerator
  }
}

// ---------------------------------------------------------------------------
// K4: wave-dot ghat = g . W2-rows (contiguous c axis), fused mask/square/trace.
// grid (64, 16) = 1024 blocks, 512 thr (32 waves/CU cap).
// ---------------------------------------------------------------------------
__global__ __launch_bounds__(512) void k_bwd1(const float* __restrict__ g,
                                              const float* __restrict__ W2,
                                              const float* __restrict__ hfinal,
                                              const float* __restrict__ xsq,
                                              float* __restrict__ bwd_part) {
  __shared__ float gs[8 * 1024];  // 32 KB, zero-padded cols from k_sample
  __shared__ float xq[8];
  __shared__ float wred[8][2];
  int jb = blockIdx.x * 16;
  int sbase = blockIdx.y * 8;
  int t = threadIdx.x;
  #pragma unroll
  for (int k = 0; k < 16; k++) {
    int idx = t + k * 512;            // 0..8191
    gs[idx] = g[(sbase + (idx >> 10)) * CP + (idx & 1023)];
  }
  if (t < 8) xq[t] = xsq[sbase + t];
  __syncthreads();

  int w = t >> 6, lane = t & 63;
  int j0 = jb + w * 2, j1 = j0 + 1;
  float a0[8] = {0,0,0,0,0,0,0,0};
  float a1[8] = {0,0,0,0,0,0,0,0};
  const float* w2r0 = W2 + (size_t)j0 * C_N;
  const float* w2r1 = W2 + (size_t)j1 * C_N;
  #pragma unroll
  for (int it = 0; it < 4; it++) {
    int c0 = it * 256 + lane * 4;
    bool act = (c0 < C_N);            // only the it==3 tail can be inactive
    float4 wv0 = act ? *reinterpret_cast<const float4*>(w2r0 + c0)
                     : make_float4(0.f, 0.f, 0.f, 0.f);
    float4 wv1 = act ? *reinterpret_cast<const float4*>(w2r1 + c0)
                     : make_float4(0.f, 0.f, 0.f, 0.f);
    #pragma unroll
    for (int s = 0; s < 8; s++) {
      float4 gv = *reinterpret_cast<const float4*>(&gs[s * 1024 + c0]);
      a0[s] += wv0.x * gv.x + wv0.y * gv.y + wv0.z * gv.z + wv0.w * gv.w;
      a1[s] += wv1.x * gv.x + wv1.y * gv.y + wv1.z * gv.z + wv1.w * gv.w;
    }
  }
  #pragma unroll
  for (int off = 32; off; off >>= 1) {
    #pragma unroll
    for (int s = 0; s < 8; s++) {
      a0[s] += __shfl_xor(a0[s], off);
      a1[s] += __shfl_xor(a1[s], off);
    }
  }
  float cb = 0.f, cw = 0.f;
  #pragma unroll
  for (int s = 0; s < 8; s++) {
    float h0 = hfinal[(sbase + s) * H_N + j0];
    float h1 = hfinal[(sbase + s) * H_N + j1];
    float v0 = (h0 > 0.f) ? a0[s] : 0.f;
    float v1 = (h1 > 0.f) ? a1[s] : 0.f;
    float q = v0 * v0 + v1 * v1;
    cb += q;
    cw += xq[s] * q;
  }
  if (lane == 0) { wred[w][0] = cw; wred[w][1] = cb; }
  __syncthreads();
  if (t == 0) {
    float sw = 0.f, sb = 0.f;
    #pragma unroll
    for (int i = 0; i < 8; i++) { sw += wred[i][0]; sb += wred[i][1]; }
    int bid = blockIdx.y * 64 + blockIdx.x;
    bwd_part[bid * 2 + 0] = sw;   // W1 trace partial
    bwd_part[bid * 2 + 1] = sb;   // b1 trace partial
  }
}

// ---------------------------------------------------------------------------
// K5: deterministic final reduction of all partials -> out[5]
// ---------------------------------------------------------------------------
__global__ __launch_bounds__(512) void k_final(const float* __restrict__ samp_part,
                                               const float* __restrict__ bwd_part,
                                               float* __restrict__ out) {
  __shared__ float red[8];
  int t = threadIdx.x;
  float w1v = bwd_part[t * 2 + 0] + bwd_part[(t + 512) * 2 + 0];
  float b1v = bwd_part[t * 2 + 1] + bwd_part[(t + 512) * 2 + 1];
  float w2v = (t < B_N) ? samp_part[t * 2 + 0] : 0.f;
  float b2v = (t < B_N) ? samp_part[t * 2 + 1] : 0.f;
  w1v = block_sum512(w1v, red);
  b1v = block_sum512(b1v, red);
  w2v = block_sum512(w2v, red);
  b2v = block_sum512(b2v, red);
  if (t == 0) {
    w1v /= 128.0f; b1v /= 128.0f; w2v /= 128.0f; b2v /= 128.0f;
    out[0] = w1v + b1v + w2v + b2v;
    out[1] = w1v;
    out[2] = b1v;
    out[3] = w2v;
    out[4] = b2v;
  }
}

// ---------------------------------------------------------------------------
extern "C" void kernel_launch(void* const* d_in, const int* in_sizes, int n_in,
                              void* d_out, int out_size, void* d_ws, size_t ws_size,
                              hipStream_t stream) {
  const float* X  = (const float*)d_in[0];
  const float* W1 = (const float*)d_in[1];
  const float* b1 = (const float*)d_in[2];
  const float* W2 = (const float*)d_in[3];
  const float* b2 = (const float*)d_in[4];
  float* out = (float*)d_out;

  float* ws        = (float*)d_ws;
  float* hpart     = ws;                        // NPART * 131072
  float* lpart     = hpart + NPART * BH;        // NPART * 131072
  float* g         = lpart + NPART * (B_N*CP);  // 131072 (stride 1024, padded)
  float* hfinal    = g + (B_N * CP);            // 131072
  float* xsq       = hfinal + BH;               // 128
  float* samp_part = xsq + 128;                 // 256
  float* bwd_part  = samp_part + 256;           // 2048

  k_fc1<<<dim3(4, 8, NPART), 256, 0, stream>>>(X, W1, hpart);
  k_fc2<<<dim3(4, 8, NPART), 256, 0, stream>>>(hpart, b1, W2, lpart);
  k_sample<<<B_N, 512, 0, stream>>>(X, hpart, b1, lpart, b2, g, hfinal, xsq, samp_part);
  k_bwd1<<<dim3(64, 16), 512, 0, stream>>>(g, W2, hfinal, xsq, bwd_part);
  k_final<<<1, 512, 0, stream>>>(samp_part, bwd_part, out);
}